// Round 2
// baseline (406.408 us; speedup 1.0000x reference)
//
#include <hip/hip_runtime.h>
#include <hip/hip_bf16.h>

typedef short short8 __attribute__((ext_vector_type(8)));
typedef unsigned short ushort8v __attribute__((ext_vector_type(8)));
typedef float f32x4 __attribute__((ext_vector_type(4)));

#define D_DIM 2048
#define KTOT 4096      // x|h concatenated along K
#define M_TOT 8192     // B*S
#define NPACK 4096     // interleaved Bi|Bc rows

// ---------------- helpers ----------------

__device__ __forceinline__ unsigned short f2bf(float f) {
    union { float f; unsigned u; } c; c.f = f;
    unsigned u = c.u;
    u += 0x7fffu + ((u >> 16) & 1u);   // round-to-nearest-even
    return (unsigned short)(u >> 16);
}

__device__ __forceinline__ float fast_tanh(float x) {
    float ax = fabsf(x);
    float ez = __expf(2.0f * fminf(ax, 15.0f));
    float t = (ez - 1.0f) / (ez + 1.0f);
    return copysignf(t, x);
}

#define GLOAD_LDS16(g, l)                                                     \
    __builtin_amdgcn_global_load_lds(                                         \
        (const __attribute__((address_space(1))) void*)(g),                   \
        (__attribute__((address_space(3))) void*)(l), 16, 0, 0)

// ---------------- pack two f32 [R][2048] matrices into bf16 [R][4096] ------

__global__ __launch_bounds__(256)
void pack2(const float* __restrict__ X, const float* __restrict__ H,
           __hip_bfloat16* __restrict__ dst, int total8) {
    int t = blockIdx.x * 256 + threadIdx.x;
    if (t >= total8) return;
    long e0 = (long)t * 8;
    long r  = e0 >> 12;            // / 4096
    int  k  = (int)(e0 & 4095);
    const float* src = (k < D_DIM) ? (X + r * D_DIM + k)
                                   : (H + r * D_DIM + (k - D_DIM));
    float4 v0 = *(const float4*)(src);
    float4 v1 = *(const float4*)(src + 4);
    ushort8v o;
    o[0] = f2bf(v0.x); o[1] = f2bf(v0.y); o[2] = f2bf(v0.z); o[3] = f2bf(v0.w);
    o[4] = f2bf(v1.x); o[5] = f2bf(v1.y); o[6] = f2bf(v1.z); o[7] = f2bf(v1.w);
    *(ushort8v*)(dst + e0) = o;
}

// ---- pack gate weights, Bi/Bc interleaved in 16-row groups ----------------
// Bpack row g: f=g>>5, w=g&31; gate=(w>>4) (0: Wi|Ui, 1: Wc|Uc);
// source n = f*16 + (w&15); cols [0,2048)=W[n], [2048,4096)=U[n].

__global__ __launch_bounds__(256)
void pack_gates(const float* __restrict__ Wi, const float* __restrict__ Ui,
                const float* __restrict__ Wc, const float* __restrict__ Uc,
                __hip_bfloat16* __restrict__ dst) {
    int t = blockIdx.x * 256 + threadIdx.x;    // 4096*512 threads
    const int g = t >> 9;
    const int k = (t & 511) * 8;
    const int w = g & 31;
    const int n = ((g >> 5) << 4) | (w & 15);
    const float* Wm = (w & 16) ? Wc : Wi;
    const float* Um = (w & 16) ? Uc : Ui;
    const float* src = (k < D_DIM) ? (Wm + (size_t)n * D_DIM + k)
                                   : (Um + (size_t)n * D_DIM + (k - D_DIM));
    float4 v0 = *(const float4*)(src);
    float4 v1 = *(const float4*)(src + 4);
    ushort8v o;
    o[0] = f2bf(v0.x); o[1] = f2bf(v0.y); o[2] = f2bf(v0.z); o[3] = f2bf(v0.w);
    o[4] = f2bf(v1.x); o[5] = f2bf(v1.y); o[6] = f2bf(v1.z); o[7] = f2bf(v1.w);
    *(ushort8v*)(dst + (size_t)g * KTOT + k) = o;
}

// ---------------- 8-phase 256x256 fused GEMM -------------------------------
// C_logical = A[8192][4096] @ Bpack[4096][4096]^T ; epilogue pairs (Zi,Zc)
// fragments (n even/odd) -> c = exp(Zi+bi)*tanh(Zc+bc), written to Cout.

#define BK 64
#define NT (KTOT / BK)   // 64 K-tiles

// stage one K-half (256 rows x 32 cols) of a tile: 2 global_load_lds / thread
// LDS dest is linear; global source pre-swizzled (u ^= row&3) so that
// swizzled ds_reads see logical data (both-sides-or-neither, rule 21).
__device__ __forceinline__ void stage_half(const __hip_bfloat16* __restrict__ mat,
                                           __hip_bfloat16* ldsHalf,
                                           int rowbase, int kcol0,
                                           int wid, int lane) {
    #pragma unroll
    for (int j = 0; j < 2; ++j) {
        const int Lb  = wid * 128 + j * 64;        // wave-uniform 16B-unit base
        const int L   = Lb + lane;
        const int row = L >> 2;
        const int ul  = (L & 3) ^ (row & 3);       // pre-swizzled source unit
        const __hip_bfloat16* src =
            mat + (size_t)(rowbase + row) * KTOT + kcol0 + ul * 8;
        GLOAD_LDS16(src, (char*)ldsHalf + Lb * 16);
    }
}

__global__ __launch_bounds__(512, 2)
void gemm8(const __hip_bfloat16* __restrict__ A,
           const __hip_bfloat16* __restrict__ Bp,
           const float* __restrict__ bWi, const float* __restrict__ bUi,
           const float* __restrict__ bWc, const float* __restrict__ bUc,
           float* __restrict__ Cout) {
    // [buf][khalf][row][32 cols] ; 4 x 16 KiB per matrix = 128 KiB total
    __shared__ __hip_bfloat16 sA[2][2][256][32];
    __shared__ __hip_bfloat16 sB[2][2][256][32];

    const int tid  = threadIdx.x;
    const int wid  = tid >> 6;
    const int lane = tid & 63;

    // XCD swizzle: 512 blocks, 512%8==0 -> bijective
    int bid = blockIdx.x;
    bid = (bid & 7) * 64 + (bid >> 3);
    const int tn = (bid & 15) * 256;   // Bpack row tile (16 tiles)
    const int tm = (bid >> 4) * 256;   // M tile (32 tiles)

    const int wr  = (wid >> 2) * 128;  // wave M offset
    const int wc  = (wid & 3) * 64;    // wave Bpack-row offset
    const int r15 = lane & 15;
    const int uswz16 = ((lane >> 4) ^ (r15 & 3)) * 16;  // swizzled 16B unit

    f32x4 acc[8][4] = {};

    // ---- prologue: stage tile 0 (A.kh0, B.kh0, A.kh1, B.kh1) ----
    stage_half(A,  &sA[0][0][0][0], tm, 0,  wid, lane);
    stage_half(Bp, &sB[0][0][0][0], tn, 0,  wid, lane);
    stage_half(A,  &sA[0][1][0][0], tm, 32, wid, lane);
    stage_half(Bp, &sB[0][1][0][0], tn, 32, wid, lane);
    asm volatile("s_waitcnt vmcnt(4)" ::: "memory");
    __builtin_amdgcn_s_barrier();

    short8 af[4], bf[4];

    for (int t = 0; t < NT; ++t) {
        const int cur = t & 1, nxt = cur ^ 1;
        const bool pf = (t + 1 < NT);
        const int kc1 = (t + 1) * BK;
        const char* pA = (const char*)sA[cur];
        const char* pB = (const char*)sB[cur];

        // ================= P1: m0-3 x n0-3, kh0 =================
        #pragma unroll
        for (int m = 0; m < 4; ++m)
            af[m] = *(const short8*)(pA + (size_t)(wr + m * 16 + r15) * 64 + uswz16);
        #pragma unroll
        for (int n = 0; n < 4; ++n)
            bf[n] = *(const short8*)(pB + (size_t)(wc + n * 16 + r15) * 64 + uswz16);
        if (pf) stage_half(A, &sA[nxt][0][0][0], tm, kc1, wid, lane);
        __builtin_amdgcn_s_barrier();
        asm volatile("s_waitcnt lgkmcnt(0)" ::: "memory");
        __builtin_amdgcn_s_setprio(1);
        #pragma unroll
        for (int m = 0; m < 4; ++m)
            #pragma unroll
            for (int n = 0; n < 4; ++n)
                acc[m][n] = __builtin_amdgcn_mfma_f32_16x16x32_bf16(
                    af[m], bf[n], acc[m][n], 0, 0, 0);
        __builtin_amdgcn_s_setprio(0);
        __builtin_amdgcn_s_barrier();

        // ================= P2: m4-7 x n0-3, kh0 (reuse bf) =================
        #pragma unroll
        for (int m = 0; m < 4; ++m)
            af[m] = *(const short8*)(pA + (size_t)(wr + 64 + m * 16 + r15) * 64 + uswz16);
        if (pf) stage_half(Bp, &sB[nxt][0][0][0], tn, kc1, wid, lane);
        __builtin_amdgcn_s_barrier();
        asm volatile("s_waitcnt lgkmcnt(0)" ::: "memory");
        __builtin_amdgcn_s_setprio(1);
        #pragma unroll
        for (int m = 0; m < 4; ++m)
            #pragma unroll
            for (int n = 0; n < 4; ++n)
                acc[4 + m][n] = __builtin_amdgcn_mfma_f32_16x16x32_bf16(
                    af[m], bf[n], acc[4 + m][n], 0, 0, 0);
        __builtin_amdgcn_s_setprio(0);
        // drain tile-t kh1 halves (needed by P3/P4); keep t+1 kh0 in flight
        if (t < NT - 1) asm volatile("s_waitcnt vmcnt(4)" ::: "memory");
        else            asm volatile("s_waitcnt vmcnt(0)" ::: "memory");
        __builtin_amdgcn_s_barrier();

        // ================= P3: m0-3 x n0-3, kh1 =================
        #pragma unroll
        for (int m = 0; m < 4; ++m)
            af[m] = *(const short8*)(pA + 16384 + (size_t)(wr + m * 16 + r15) * 64 + uswz16);
        #pragma unroll
        for (int n = 0; n < 4; ++n)
            bf[n] = *(const short8*)(pB + 16384 + (size_t)(wc + n * 16 + r15) * 64 + uswz16);
        if (pf) stage_half(A, &sA[nxt][1][0][0], tm, kc1 + 32, wid, lane);
        __builtin_amdgcn_s_barrier();
        asm volatile("s_waitcnt lgkmcnt(0)" ::: "memory");
        __builtin_amdgcn_s_setprio(1);
        #pragma unroll
        for (int m = 0; m < 4; ++m)
            #pragma unroll
            for (int n = 0; n < 4; ++n)
                acc[m][n] = __builtin_amdgcn_mfma_f32_16x16x32_bf16(
                    af[m], bf[n], acc[m][n], 0, 0, 0);
        __builtin_amdgcn_s_setprio(0);
        __builtin_amdgcn_s_barrier();

        // ================= P4: m4-7 x n0-3, kh1 (reuse bf) =================
        #pragma unroll
        for (int m = 0; m < 4; ++m)
            af[m] = *(const short8*)(pA + 16384 + (size_t)(wr + 64 + m * 16 + r15) * 64 + uswz16);
        if (pf) stage_half(Bp, &sB[nxt][1][0][0], tn, kc1 + 32, wid, lane);
        __builtin_amdgcn_s_barrier();
        asm volatile("s_waitcnt lgkmcnt(0)" ::: "memory");
        __builtin_amdgcn_s_setprio(1);
        #pragma unroll
        for (int m = 0; m < 4; ++m)
            #pragma unroll
            for (int n = 0; n < 4; ++n)
                acc[4 + m][n] = __builtin_amdgcn_mfma_f32_16x16x32_bf16(
                    af[m], bf[n], acc[4 + m][n], 0, 0, 0);
        __builtin_amdgcn_s_setprio(0);
        // drain t+1 kh0 halves (needed by next P1/P2); keep t+1 kh1 in flight
        asm volatile("s_waitcnt vmcnt(4)" ::: "memory");
        __builtin_amdgcn_s_barrier();
    }

    // ---- epilogue: pair (Zi,Zc) fragments -> c = exp(Zi)*tanh(Zc) ----
    const int rg4 = (lane >> 4) * 4;
    #pragma unroll
    for (int q = 0; q < 2; ++q) {
        const int gn = (tn >> 1) + (wc >> 1) + q * 16 + r15;
        const float bi_ = bWi[gn] + bUi[gn];
        const float bc_ = bWc[gn] + bUc[gn];
        #pragma unroll
        for (int m = 0; m < 8; ++m) {
            const int gm = tm + wr + m * 16 + rg4;
            #pragma unroll
            for (int r = 0; r < 4; ++r) {
                const float zi = acc[m][2 * q][r]     + bi_;
                const float zc = acc[m][2 * q + 1][r] + bc_;
                Cout[(size_t)(gm + r) * D_DIM + gn] = __expf(zi) * fast_tanh(zc);
            }
        }
    }
}

// ---------------- last-timestep o-gate: hbuf[b][e] = sig(Zo)*tanh(c) -------

__global__ __launch_bounds__(256)
void last_gate(const float* __restrict__ x, const float* __restrict__ h,
               const float* __restrict__ Wo, const float* __restrict__ bWo,
               const float* __restrict__ Uo, const float* __restrict__ bUo,
               const float* __restrict__ cfull, float* __restrict__ hbuf) {
    const int o    = blockIdx.x * 4 + (threadIdx.x >> 6);
    const int lane = threadIdx.x & 63;
    const int b = o >> 11, e = o & 2047;
    const float* xr = x  + ((size_t)b * D_DIM + (D_DIM - 1)) * D_DIM;
    const float* hr = h  + ((size_t)b * D_DIM + (D_DIM - 1)) * D_DIM;
    const float* wo = Wo + (size_t)e * D_DIM;
    const float* uo = Uo + (size_t)e * D_DIM;
    float s = 0.0f;
    for (int d = lane; d < D_DIM; d += 64)
        s += xr[d] * wo[d] + hr[d] * uo[d];
    #pragma unroll
    for (int off = 32; off; off >>= 1) s += __shfl_down(s, off);
    if (lane == 0) {
        const float zo  = s + bWo[e] + bUo[e];
        const float sig = 1.0f / (1.0f + __expf(-zo));
        const float cv  = cfull[((size_t)b * D_DIM + (D_DIM - 1)) * D_DIM + e];
        hbuf[o] = sig * fast_tanh(cv);
    }
}

// ---------------- final projection: out[b][p] = hbuf[b] . Wp[p] + bp[p] ----

__global__ __launch_bounds__(256)
void proj(const float* __restrict__ hbuf, const float* __restrict__ Wp,
          const float* __restrict__ bp, float* __restrict__ out) {
    const int o    = blockIdx.x * 4 + (threadIdx.x >> 6);
    const int lane = threadIdx.x & 63;
    const int b = o >> 11, p = o & 2047;
    const float* hv = hbuf + (size_t)b * D_DIM;
    const float* wp = Wp   + (size_t)p * D_DIM;
    float s = 0.0f;
    for (int e = lane; e < D_DIM; e += 64)
        s += hv[e] * wp[e];
    #pragma unroll
    for (int off = 32; off; off >>= 1) s += __shfl_down(s, off);
    if (lane == 0) out[o] = s + bp[p];
}

// ---------------- launch ---------------------------------------------------

extern "C" void kernel_launch(void* const* d_in, const int* in_sizes, int n_in,
                              void* d_out, int out_size, void* d_ws, size_t ws_size,
                              hipStream_t stream) {
    const float* x   = (const float*)d_in[0];
    const float* h   = (const float*)d_in[1];
    const float* Wi  = (const float*)d_in[2];  const float* bWi = (const float*)d_in[3];
    const float* Ui  = (const float*)d_in[4];  const float* bUi = (const float*)d_in[5];
    // Wf/bWf/Uf/bUf (6..9) are dead: f-gate multiplies a zero cell state
    const float* Wc  = (const float*)d_in[10]; const float* bWc = (const float*)d_in[11];
    const float* Uc  = (const float*)d_in[12]; const float* bUc = (const float*)d_in[13];
    const float* Wo  = (const float*)d_in[14]; const float* bWo = (const float*)d_in[15];
    const float* Uo  = (const float*)d_in[16]; const float* bUo = (const float*)d_in[17];
    const float* Wp  = (const float*)d_in[18]; const float* bp  = (const float*)d_in[19];

    float* out = (float*)d_out;               // [0,8192) hidden_state, then c
    char*  ws  = (char*)d_ws;

    __hip_bfloat16* Abf  = (__hip_bfloat16*)ws;                          // 64 MiB
    __hip_bfloat16* Bpk  = (__hip_bfloat16*)(ws + ((size_t)64 << 20));   // 32 MiB
    float*          hbuf = (float*)(ws + ((size_t)96 << 20));            // 32 KiB

    // 1) convert/pack to bf16
    pack2<<<16384, 256, 0, stream>>>(x, h, Abf, M_TOT * KTOT / 8);
    pack_gates<<<8192, 256, 0, stream>>>(Wi, Ui, Wc, Uc, Bpk);

    // 2) fused dual-gate 8-phase GEMM -> c
    gemm8<<<(M_TOT / 256) * (NPACK / 256), 512, 0, stream>>>(
        Abf, Bpk, bWi, bUi, bWc, bUc, out + 8192);

    // 3) last-timestep o-gate (reads c from out), then 4) projection
    last_gate<<<2048, 256, 0, stream>>>(x, h, Wo, bWo, Uo, bUo, out + 8192,
                                        (float*)hbuf);
    proj<<<2048, 256, 0, stream>>>(hbuf, Wp, bp, out);
}

// Round 3
// 374.178 us; speedup vs baseline: 1.0861x; 1.0861x over previous
//
#include <hip/hip_runtime.h>
#include <hip/hip_bf16.h>

typedef short short8 __attribute__((ext_vector_type(8)));
typedef unsigned short ushort8v __attribute__((ext_vector_type(8)));
typedef float f32x4 __attribute__((ext_vector_type(4)));

#define D_DIM 2048
#define KTOT 4096      // x|h concatenated along K
#define M_TOT 8192     // B*S
#define NPACK 4096     // interleaved Bi|Bc rows

// ---------------- helpers ----------------

__device__ __forceinline__ unsigned short f2bf(float f) {
    union { float f; unsigned u; } c; c.f = f;
    unsigned u = c.u;
    u += 0x7fffu + ((u >> 16) & 1u);   // round-to-nearest-even
    return (unsigned short)(u >> 16);
}

__device__ __forceinline__ float fast_tanh(float x) {
    float ax = fabsf(x);
    float ez = __expf(2.0f * fminf(ax, 15.0f));
    float t = (ez - 1.0f) / (ez + 1.0f);
    return copysignf(t, x);
}

#define GLOAD_LDS16(g, l)                                                     \
    __builtin_amdgcn_global_load_lds(                                         \
        (const __attribute__((address_space(1))) void*)(g),                   \
        (__attribute__((address_space(3))) void*)(l), 16, 0, 0)

// ---------------- pack two f32 [R][2048] matrices into bf16 [R][4096] ------

__global__ __launch_bounds__(256)
void pack2(const float* __restrict__ X, const float* __restrict__ H,
           __hip_bfloat16* __restrict__ dst, int total8) {
    int t = blockIdx.x * 256 + threadIdx.x;
    if (t >= total8) return;
    long e0 = (long)t * 8;
    long r  = e0 >> 12;            // / 4096
    int  k  = (int)(e0 & 4095);
    const float* src = (k < D_DIM) ? (X + r * D_DIM + k)
                                   : (H + r * D_DIM + (k - D_DIM));
    float4 v0 = *(const float4*)(src);
    float4 v1 = *(const float4*)(src + 4);
    ushort8v o;
    o[0] = f2bf(v0.x); o[1] = f2bf(v0.y); o[2] = f2bf(v0.z); o[3] = f2bf(v0.w);
    o[4] = f2bf(v1.x); o[5] = f2bf(v1.y); o[6] = f2bf(v1.z); o[7] = f2bf(v1.w);
    *(ushort8v*)(dst + e0) = o;
}

// ---- pack gate weights, Bi/Bc interleaved in 16-row groups ----------------
// Bpack row g: f=g>>5, w=g&31; gate=(w>>4) (0: Wi|Ui, 1: Wc|Uc);
// source n = f*16 + (w&15); cols [0,2048)=W[n], [2048,4096)=U[n].

__global__ __launch_bounds__(256)
void pack_gates(const float* __restrict__ Wi, const float* __restrict__ Ui,
                const float* __restrict__ Wc, const float* __restrict__ Uc,
                __hip_bfloat16* __restrict__ dst) {
    int t = blockIdx.x * 256 + threadIdx.x;    // 4096*512 threads
    const int g = t >> 9;
    const int k = (t & 511) * 8;
    const int w = g & 31;
    const int n = ((g >> 5) << 4) | (w & 15);
    const float* Wm = (w & 16) ? Wc : Wi;
    const float* Um = (w & 16) ? Uc : Ui;
    const float* src = (k < D_DIM) ? (Wm + (size_t)n * D_DIM + k)
                                   : (Um + (size_t)n * D_DIM + (k - D_DIM));
    float4 v0 = *(const float4*)(src);
    float4 v1 = *(const float4*)(src + 4);
    ushort8v o;
    o[0] = f2bf(v0.x); o[1] = f2bf(v0.y); o[2] = f2bf(v0.z); o[3] = f2bf(v0.w);
    o[4] = f2bf(v1.x); o[5] = f2bf(v1.y); o[6] = f2bf(v1.z); o[7] = f2bf(v1.w);
    *(ushort8v*)(dst + (size_t)g * KTOT + k) = o;
}

// ---------------- 8-phase 256x256 fused GEMM -------------------------------
// C_logical = A[8192][4096] @ Bpack[4096][4096]^T ; epilogue pairs (Zi,Zc)
// fragments (n even/odd) -> c = exp(Zi+bi)*tanh(Zc+bc), written to Cout.
//
// LDS swizzle: rows are 64 B = 4x16B units; bank-quad = (row&1)*4 + unit.
// Store logical unit g at position p = g ^ ((row>>1)&3). Over 16 consecutive
// rows x 4 lane-groups every quad gets exactly 8 lanes -> conflict-free
// wave64 ds_read_b128 (8-clock minimum). Source is pre-swizzled so the
// linear global_load_lds dest + swizzled ds_read agree (rule 21).

#define BK 64
#define NT (KTOT / BK)   // 64 K-tiles

__device__ __forceinline__ void stage_half(const __hip_bfloat16* __restrict__ mat,
                                           __hip_bfloat16* ldsHalf,
                                           int rowbase, int kcol0,
                                           int wid, int lane) {
    #pragma unroll
    for (int j = 0; j < 2; ++j) {
        const int Lb  = wid * 128 + j * 64;        // wave-uniform 16B-unit base
        const int L   = Lb + lane;
        const int row = L >> 2;
        const int ul  = (L & 3) ^ ((L >> 3) & 3);  // pre-swizzled source unit
        const __hip_bfloat16* src =
            mat + (size_t)(rowbase + row) * KTOT + kcol0 + ul * 8;
        GLOAD_LDS16(src, (char*)ldsHalf + Lb * 16);
    }
}

__global__ __launch_bounds__(512, 2)
void gemm8(const __hip_bfloat16* __restrict__ A,
           const __hip_bfloat16* __restrict__ Bp,
           const float* __restrict__ bWi, const float* __restrict__ bUi,
           const float* __restrict__ bWc, const float* __restrict__ bUc,
           float* __restrict__ Cout) {
    // [buf][khalf][row][32 cols] ; 4 x 16 KiB per matrix = 128 KiB total
    __shared__ __hip_bfloat16 sA[2][2][256][32];
    __shared__ __hip_bfloat16 sB[2][2][256][32];

    const int tid  = threadIdx.x;
    const int wid  = tid >> 6;
    const int lane = tid & 63;

    // XCD swizzle: 512 blocks, 512%8==0 -> bijective
    int bid = blockIdx.x;
    bid = (bid & 7) * 64 + (bid >> 3);
    const int tn = (bid & 15) * 256;   // Bpack row tile (16 tiles)
    const int tm = (bid >> 4) * 256;   // M tile (32 tiles)

    const int wr  = (wid >> 2) * 128;  // wave M offset
    const int wc  = (wid & 3) * 64;    // wave Bpack-row offset
    const int r15 = lane & 15;
    // balanced-quad swizzled 16B-unit byte offset (see header comment)
    const int uswz16 = (((lane >> 4) ^ ((r15 >> 1) & 3)) * 16);

    f32x4 acc[8][4] = {};

    // ---- prologue: stage tile 0 (A.kh0, B.kh0, A.kh1, B.kh1) ----
    stage_half(A,  &sA[0][0][0][0], tm, 0,  wid, lane);
    stage_half(Bp, &sB[0][0][0][0], tn, 0,  wid, lane);
    stage_half(A,  &sA[0][1][0][0], tm, 32, wid, lane);
    stage_half(Bp, &sB[0][1][0][0], tn, 32, wid, lane);
    asm volatile("s_waitcnt vmcnt(4)" ::: "memory");
    __builtin_amdgcn_s_barrier();

    short8 af[4], bf[4];

    for (int t = 0; t < NT; ++t) {
        const int cur = t & 1, nxt = cur ^ 1;
        const bool pf = (t + 1 < NT);
        const int kc1 = (t + 1) * BK;
        const char* pA = (const char*)sA[cur];
        const char* pB = (const char*)sB[cur];

        // ================= P1: m0-3 x n0-3, kh0 =================
        #pragma unroll
        for (int m = 0; m < 4; ++m)
            af[m] = *(const short8*)(pA + (size_t)(wr + m * 16 + r15) * 64 + uswz16);
        #pragma unroll
        for (int n = 0; n < 4; ++n)
            bf[n] = *(const short8*)(pB + (size_t)(wc + n * 16 + r15) * 64 + uswz16);
        if (pf) stage_half(A, &sA[nxt][0][0][0], tm, kc1, wid, lane);
        __builtin_amdgcn_s_barrier();
        asm volatile("s_waitcnt lgkmcnt(0)" ::: "memory");
        __builtin_amdgcn_s_setprio(1);
        #pragma unroll
        for (int m = 0; m < 4; ++m)
            #pragma unroll
            for (int n = 0; n < 4; ++n)
                acc[m][n] = __builtin_amdgcn_mfma_f32_16x16x32_bf16(
                    af[m], bf[n], acc[m][n], 0, 0, 0);
        __builtin_amdgcn_s_setprio(0);
        __builtin_amdgcn_s_barrier();

        // ================= P2: m4-7 x n0-3, kh0 (reuse bf) =================
        #pragma unroll
        for (int m = 0; m < 4; ++m)
            af[m] = *(const short8*)(pA + (size_t)(wr + 64 + m * 16 + r15) * 64 + uswz16);
        if (pf) stage_half(Bp, &sB[nxt][0][0][0], tn, kc1, wid, lane);
        __builtin_amdgcn_s_barrier();
        asm volatile("s_waitcnt lgkmcnt(0)" ::: "memory");
        __builtin_amdgcn_s_setprio(1);
        #pragma unroll
        for (int m = 0; m < 4; ++m)
            #pragma unroll
            for (int n = 0; n < 4; ++n)
                acc[4 + m][n] = __builtin_amdgcn_mfma_f32_16x16x32_bf16(
                    af[m], bf[n], acc[4 + m][n], 0, 0, 0);
        __builtin_amdgcn_s_setprio(0);
        // drain tile-t kh1 halves (needed by P3/P4); keep t+1 kh0 in flight
        if (t < NT - 1) asm volatile("s_waitcnt vmcnt(4)" ::: "memory");
        else            asm volatile("s_waitcnt vmcnt(0)" ::: "memory");
        __builtin_amdgcn_s_barrier();

        // ================= P3: m0-3 x n0-3, kh1 =================
        #pragma unroll
        for (int m = 0; m < 4; ++m)
            af[m] = *(const short8*)(pA + 16384 + (size_t)(wr + m * 16 + r15) * 64 + uswz16);
        #pragma unroll
        for (int n = 0; n < 4; ++n)
            bf[n] = *(const short8*)(pB + 16384 + (size_t)(wc + n * 16 + r15) * 64 + uswz16);
        if (pf) stage_half(A, &sA[nxt][1][0][0], tm, kc1 + 32, wid, lane);
        __builtin_amdgcn_s_barrier();
        asm volatile("s_waitcnt lgkmcnt(0)" ::: "memory");
        __builtin_amdgcn_s_setprio(1);
        #pragma unroll
        for (int m = 0; m < 4; ++m)
            #pragma unroll
            for (int n = 0; n < 4; ++n)
                acc[m][n] = __builtin_amdgcn_mfma_f32_16x16x32_bf16(
                    af[m], bf[n], acc[m][n], 0, 0, 0);
        __builtin_amdgcn_s_setprio(0);
        __builtin_amdgcn_s_barrier();

        // ================= P4: m4-7 x n0-3, kh1 (reuse bf) =================
        #pragma unroll
        for (int m = 0; m < 4; ++m)
            af[m] = *(const short8*)(pA + 16384 + (size_t)(wr + 64 + m * 16 + r15) * 64 + uswz16);
        if (pf) stage_half(Bp, &sB[nxt][1][0][0], tn, kc1 + 32, wid, lane);
        __builtin_amdgcn_s_barrier();
        asm volatile("s_waitcnt lgkmcnt(0)" ::: "memory");
        __builtin_amdgcn_s_setprio(1);
        #pragma unroll
        for (int m = 0; m < 4; ++m)
            #pragma unroll
            for (int n = 0; n < 4; ++n)
                acc[4 + m][n] = __builtin_amdgcn_mfma_f32_16x16x32_bf16(
                    af[m], bf[n], acc[4 + m][n], 0, 0, 0);
        __builtin_amdgcn_s_setprio(0);
        // drain t+1 kh0 halves (needed by next P1/P2); keep t+1 kh1 in flight
        asm volatile("s_waitcnt vmcnt(4)" ::: "memory");
        __builtin_amdgcn_s_barrier();
    }

    // ---- epilogue: pair (Zi,Zc) fragments -> c = exp(Zi)*tanh(Zc) ----
    const int rg4 = (lane >> 4) * 4;
    #pragma unroll
    for (int q = 0; q < 2; ++q) {
        const int gn = (tn >> 1) + (wc >> 1) + q * 16 + r15;
        const float bi_ = bWi[gn] + bUi[gn];
        const float bc_ = bWc[gn] + bUc[gn];
        #pragma unroll
        for (int m = 0; m < 8; ++m) {
            const int gm = tm + wr + m * 16 + rg4;
            #pragma unroll
            for (int r = 0; r < 4; ++r) {
                const float zi = acc[m][2 * q][r]     + bi_;
                const float zc = acc[m][2 * q + 1][r] + bc_;
                Cout[(size_t)(gm + r) * D_DIM + gn] = __expf(zi) * fast_tanh(zc);
            }
        }
    }
}

// ---------------- last-timestep o-gate: hbuf[b][e] = sig(Zo)*tanh(c) -------

__global__ __launch_bounds__(256)
void last_gate(const float* __restrict__ x, const float* __restrict__ h,
               const float* __restrict__ Wo, const float* __restrict__ bWo,
               const float* __restrict__ Uo, const float* __restrict__ bUo,
               const float* __restrict__ cfull, float* __restrict__ hbuf) {
    const int o    = blockIdx.x * 4 + (threadIdx.x >> 6);
    const int lane = threadIdx.x & 63;
    const int b = o >> 11, e = o & 2047;
    const float* xr = x  + ((size_t)b * D_DIM + (D_DIM - 1)) * D_DIM;
    const float* hr = h  + ((size_t)b * D_DIM + (D_DIM - 1)) * D_DIM;
    const float* wo = Wo + (size_t)e * D_DIM;
    const float* uo = Uo + (size_t)e * D_DIM;
    float s = 0.0f;
    for (int d = lane; d < D_DIM; d += 64)
        s += xr[d] * wo[d] + hr[d] * uo[d];
    #pragma unroll
    for (int off = 32; off; off >>= 1) s += __shfl_down(s, off);
    if (lane == 0) {
        const float zo  = s + bWo[e] + bUo[e];
        const float sig = 1.0f / (1.0f + __expf(-zo));
        const float cv  = cfull[((size_t)b * D_DIM + (D_DIM - 1)) * D_DIM + e];
        hbuf[o] = sig * fast_tanh(cv);
    }
}

// ---------------- final projection: out[b][p] = hbuf[b] . Wp[p] + bp[p] ----

__global__ __launch_bounds__(256)
void proj(const float* __restrict__ hbuf, const float* __restrict__ Wp,
          const float* __restrict__ bp, float* __restrict__ out) {
    const int o    = blockIdx.x * 4 + (threadIdx.x >> 6);
    const int lane = threadIdx.x & 63;
    const int b = o >> 11, p = o & 2047;
    const float* hv = hbuf + (size_t)b * D_DIM;
    const float* wp = Wp   + (size_t)p * D_DIM;
    float s = 0.0f;
    for (int e = lane; e < D_DIM; e += 64)
        s += hv[e] * wp[e];
    #pragma unroll
    for (int off = 32; off; off >>= 1) s += __shfl_down(s, off);
    if (lane == 0) out[o] = s + bp[p];
}

// ---------------- launch ---------------------------------------------------

extern "C" void kernel_launch(void* const* d_in, const int* in_sizes, int n_in,
                              void* d_out, int out_size, void* d_ws, size_t ws_size,
                              hipStream_t stream) {
    const float* x   = (const float*)d_in[0];
    const float* h   = (const float*)d_in[1];
    const float* Wi  = (const float*)d_in[2];  const float* bWi = (const float*)d_in[3];
    const float* Ui  = (const float*)d_in[4];  const float* bUi = (const float*)d_in[5];
    // Wf/bWf/Uf/bUf (6..9) are dead: f-gate multiplies a zero cell state
    const float* Wc  = (const float*)d_in[10]; const float* bWc = (const float*)d_in[11];
    const float* Uc  = (const float*)d_in[12]; const float* bUc = (const float*)d_in[13];
    const float* Wo  = (const float*)d_in[14]; const float* bWo = (const float*)d_in[15];
    const float* Uo  = (const float*)d_in[16]; const float* bUo = (const float*)d_in[17];
    const float* Wp  = (const float*)d_in[18]; const float* bp  = (const float*)d_in[19];

    float* out = (float*)d_out;               // [0,8192) hidden_state, then c
    char*  ws  = (char*)d_ws;

    __hip_bfloat16* Abf  = (__hip_bfloat16*)ws;                          // 64 MiB
    __hip_bfloat16* Bpk  = (__hip_bfloat16*)(ws + ((size_t)64 << 20));   // 32 MiB
    float*          hbuf = (float*)(ws + ((size_t)96 << 20));            // 32 KiB

    // 1) convert/pack to bf16
    pack2<<<16384, 256, 0, stream>>>(x, h, Abf, M_TOT * KTOT / 8);
    pack_gates<<<8192, 256, 0, stream>>>(Wi, Ui, Wc, Uc, Bpk);

    // 2) fused dual-gate 8-phase GEMM -> c
    gemm8<<<(M_TOT / 256) * (NPACK / 256), 512, 0, stream>>>(
        Abf, Bpk, bWi, bUi, bWc, bUc, out + 8192);

    // 3) last-timestep o-gate (reads c from out), then 4) projection
    last_gate<<<2048, 256, 0, stream>>>(x, h, Wo, bWo, Uo, bUo, out + 8192,
                                        (float*)hbuf);
    proj<<<2048, 256, 0, stream>>>(hbuf, Wp, bp, out);
}

// Round 4
// 334.638 us; speedup vs baseline: 1.2145x; 1.1182x over previous
//
#include <hip/hip_runtime.h>
#include <hip/hip_bf16.h>

typedef short short8 __attribute__((ext_vector_type(8)));
typedef unsigned short ushort8v __attribute__((ext_vector_type(8)));
typedef float f32x4 __attribute__((ext_vector_type(4)));

#define D_DIM 2048
#define KTOT 4096      // x|h concatenated along K
#define M_TOT 8192     // B*S
#define NPACK 4096     // interleaved Bi|Bc rows

// ---------------- helpers ----------------

__device__ __forceinline__ unsigned short f2bf(float f) {
    union { float f; unsigned u; } c; c.f = f;
    unsigned u = c.u;
    u += 0x7fffu + ((u >> 16) & 1u);   // round-to-nearest-even
    return (unsigned short)(u >> 16);
}

__device__ __forceinline__ float fast_tanh(float x) {
    float ax = fabsf(x);
    float ez = __expf(2.0f * fminf(ax, 15.0f));
    float t = (ez - 1.0f) / (ez + 1.0f);
    return copysignf(t, x);
}

#define GLOAD_LDS16(g, l)                                                     \
    __builtin_amdgcn_global_load_lds(                                         \
        (const __attribute__((address_space(1))) void*)(g),                   \
        (__attribute__((address_space(3))) void*)(l), 16, 0, 0)

// ---------------- pack two f32 [R][2048] matrices into bf16 [R][4096] ------

__global__ __launch_bounds__(256)
void pack2(const float* __restrict__ X, const float* __restrict__ H,
           __hip_bfloat16* __restrict__ dst, int total8) {
    int t = blockIdx.x * 256 + threadIdx.x;
    if (t >= total8) return;
    long e0 = (long)t * 8;
    long r  = e0 >> 12;            // / 4096
    int  k  = (int)(e0 & 4095);
    const float* src = (k < D_DIM) ? (X + r * D_DIM + k)
                                   : (H + r * D_DIM + (k - D_DIM));
    float4 v0 = *(const float4*)(src);
    float4 v1 = *(const float4*)(src + 4);
    ushort8v o;
    o[0] = f2bf(v0.x); o[1] = f2bf(v0.y); o[2] = f2bf(v0.z); o[3] = f2bf(v0.w);
    o[4] = f2bf(v1.x); o[5] = f2bf(v1.y); o[6] = f2bf(v1.z); o[7] = f2bf(v1.w);
    *(ushort8v*)(dst + e0) = o;
}

// ---- pack gate weights, Bi/Bc interleaved in 16-row groups ----------------

__global__ __launch_bounds__(256)
void pack_gates(const float* __restrict__ Wi, const float* __restrict__ Ui,
                const float* __restrict__ Wc, const float* __restrict__ Uc,
                __hip_bfloat16* __restrict__ dst) {
    int t = blockIdx.x * 256 + threadIdx.x;    // 4096*512 threads
    const int g = t >> 9;
    const int k = (t & 511) * 8;
    const int w = g & 31;
    const int n = ((g >> 5) << 4) | (w & 15);
    const float* Wm = (w & 16) ? Wc : Wi;
    const float* Um = (w & 16) ? Uc : Ui;
    const float* src = (k < D_DIM) ? (Wm + (size_t)n * D_DIM + k)
                                   : (Um + (size_t)n * D_DIM + (k - D_DIM));
    float4 v0 = *(const float4*)(src);
    float4 v1 = *(const float4*)(src + 4);
    ushort8v o;
    o[0] = f2bf(v0.x); o[1] = f2bf(v0.y); o[2] = f2bf(v0.z); o[3] = f2bf(v0.w);
    o[4] = f2bf(v1.x); o[5] = f2bf(v1.y); o[6] = f2bf(v1.z); o[7] = f2bf(v1.w);
    *(ushort8v*)(dst + (size_t)g * KTOT + k) = o;
}

// ---------------- 8-phase 256x256 fused GEMM, reg-pipelined ----------------
// Fragments for phase p+1 are ds_read during phase p; the counted
// lgkmcnt(N_issued) before each MFMA cluster waits only for the previous
// phase's reads, so the LDS pipe serves next-phase reads WHILE the matrix
// pipe runs this phase's 16 MFMAs. One barrier per phase; counted vmcnt(2)
// drains at P1 (kh1 of tile t) and P3 (kh0 of tile t+1) only.

#define BK 64
#define NT (KTOT / BK)   // 64 K-tiles

__device__ __forceinline__ void stage_half(const __hip_bfloat16* __restrict__ mat,
                                           __hip_bfloat16* ldsHalf,
                                           int rowbase, int kcol0,
                                           int wid, int lane) {
    #pragma unroll
    for (int j = 0; j < 2; ++j) {
        const int Lb  = wid * 128 + j * 64;        // wave-uniform 16B-unit base
        const int L   = Lb + lane;
        const int row = L >> 2;
        const int ul  = (L & 3) ^ ((L >> 3) & 3);  // pre-swizzled source unit
        const __hip_bfloat16* src =
            mat + (size_t)(rowbase + row) * KTOT + kcol0 + ul * 8;
        GLOAD_LDS16(src, (char*)ldsHalf + Lb * 16);
    }
}

__device__ __forceinline__ void read4(short8 (&dst)[4], const char* base,
                                      int roff, int uswz16) {
    #pragma unroll
    for (int m = 0; m < 4; ++m)
        dst[m] = *(const short8*)(base + (size_t)(roff + m * 16) * 64 + uswz16);
}

__device__ __forceinline__ void mfma16(f32x4 (&acc)[8][4], int mb,
                                       const short8 (&a)[4], const short8 (&b)[4]) {
    #pragma unroll
    for (int m = 0; m < 4; ++m)
        #pragma unroll
        for (int n = 0; n < 4; ++n)
            acc[mb + m][n] = __builtin_amdgcn_mfma_f32_16x16x32_bf16(
                a[m], b[n], acc[mb + m][n], 0, 0, 0);
}

__global__ __launch_bounds__(512, 2)
void gemm8(const __hip_bfloat16* __restrict__ A,
           const __hip_bfloat16* __restrict__ Bp,
           const float* __restrict__ bWi, const float* __restrict__ bUi,
           const float* __restrict__ bWc, const float* __restrict__ bUc,
           float* __restrict__ Cout) {
    // [buf][khalf][row][32 cols] ; 4 x 16 KiB per matrix = 128 KiB total
    __shared__ __hip_bfloat16 sA[2][2][256][32];
    __shared__ __hip_bfloat16 sB[2][2][256][32];

    const int tid  = threadIdx.x;
    const int wid  = tid >> 6;
    const int lane = tid & 63;

    // XCD swizzle: 512 blocks, 512%8==0 -> bijective
    int bid = blockIdx.x;
    bid = (bid & 7) * 64 + (bid >> 3);
    const int tn = (bid & 15) * 256;   // Bpack row tile (16 tiles)
    const int tm = (bid >> 4) * 256;   // M tile (32 tiles)

    const int wr  = (wid >> 2) * 128;  // wave M offset
    const int wc  = (wid & 3) * 64;    // wave Bpack-row offset
    const int r15 = lane & 15;
    // balanced-quad swizzle: unit p = g ^ ((row>>1)&3); conflict-free b128
    const int uswz16 = (((lane >> 4) ^ ((r15 >> 1) & 3)) * 16);

    const int rA  = wr + r15;          // A-read row base (+64 for m4-7)
    const int rB  = wc + r15;          // B-read row base

    f32x4 acc[8][4] = {};
    short8 aP[4], aQ[4], bP[4], bQ[4];

    // ---- prologue: stage tile 0, drain kh0, read P1 frags ----
    stage_half(A,  &sA[0][0][0][0], tm, 0,  wid, lane);
    stage_half(Bp, &sB[0][0][0][0], tn, 0,  wid, lane);
    stage_half(A,  &sA[0][1][0][0], tm, 32, wid, lane);
    stage_half(Bp, &sB[0][1][0][0], tn, 32, wid, lane);
    asm volatile("s_waitcnt vmcnt(4)" ::: "memory");
    __builtin_amdgcn_s_barrier();
    read4(aP, (const char*)&sA[0][0][0][0], rA, uswz16);
    read4(bP, (const char*)&sB[0][0][0][0], rB, uswz16);

    for (int t = 0; t < NT; ++t) {
        const int cur = t & 1, nxt = cur ^ 1;
        const bool pf = (t + 1 < NT);
        const int kc1 = (t + 1) * BK;
        const char* cA0 = (const char*)&sA[cur][0][0][0];
        const char* cA1 = (const char*)&sA[cur][1][0][0];
        const char* cB1 = (const char*)&sB[cur][1][0][0];
        const char* nA0 = (const char*)&sA[nxt][0][0][0];
        const char* nB0 = (const char*)&sB[nxt][0][0][0];

        // ---- P1: MFMA aP x bP (kh0, m0-3); read aQ (kh0 m4-7) ----
        read4(aQ, cA0, rA + 64, uswz16);
        if (pf) {
            stage_half(A, &sA[nxt][0][0][0], tm, kc1, wid, lane);
            asm volatile("s_waitcnt vmcnt(2)" ::: "memory");   // kh1(t) landed
        } else {
            asm volatile("s_waitcnt vmcnt(0)" ::: "memory");
        }
        __builtin_amdgcn_s_barrier();
        asm volatile("s_waitcnt lgkmcnt(4)" ::: "memory");
        __builtin_amdgcn_sched_barrier(0);
        __builtin_amdgcn_s_setprio(1);
        mfma16(acc, 0, aP, bP);
        __builtin_amdgcn_s_setprio(0);

        // ---- P2: MFMA aQ x bP (kh0, m4-7); read aP,bQ (kh1) ----
        read4(aP, cA1, rA, uswz16);
        read4(bQ, cB1, rB, uswz16);
        if (pf) stage_half(Bp, &sB[nxt][0][0][0], tn, kc1, wid, lane);
        __builtin_amdgcn_s_barrier();
        asm volatile("s_waitcnt lgkmcnt(8)" ::: "memory");
        __builtin_amdgcn_sched_barrier(0);
        __builtin_amdgcn_s_setprio(1);
        mfma16(acc, 4, aQ, bP);
        __builtin_amdgcn_s_setprio(0);

        // ---- P3: MFMA aP x bQ (kh1, m0-3); read aQ (kh1 m4-7) ----
        read4(aQ, cA1, rA + 64, uswz16);
        if (pf) {
            stage_half(A, &sA[nxt][1][0][0], tm, kc1 + 32, wid, lane);
            asm volatile("s_waitcnt vmcnt(2)" ::: "memory");   // kh0(t+1) landed
        } else {
            asm volatile("s_waitcnt vmcnt(0)" ::: "memory");
        }
        __builtin_amdgcn_s_barrier();
        asm volatile("s_waitcnt lgkmcnt(4)" ::: "memory");
        __builtin_amdgcn_sched_barrier(0);
        __builtin_amdgcn_s_setprio(1);
        mfma16(acc, 0, aP, bQ);
        __builtin_amdgcn_s_setprio(0);

        // ---- P4: MFMA aQ x bQ (kh1, m4-7); read aP,bP (next tile kh0) ----
        if (pf) {
            read4(aP, nA0, rA, uswz16);
            read4(bP, nB0, rB, uswz16);
            stage_half(Bp, &sB[nxt][1][0][0], tn, kc1 + 32, wid, lane);
        }
        __builtin_amdgcn_s_barrier();
        if (pf) asm volatile("s_waitcnt lgkmcnt(8)" ::: "memory");
        else    asm volatile("s_waitcnt lgkmcnt(0)" ::: "memory");
        __builtin_amdgcn_sched_barrier(0);
        __builtin_amdgcn_s_setprio(1);
        mfma16(acc, 4, aQ, bQ);
        __builtin_amdgcn_s_setprio(0);
    }

    // ---- epilogue: pair (Zi,Zc) fragments -> c = exp(Zi)*tanh(Zc) ----
    const int rg4 = (lane >> 4) * 4;
    #pragma unroll
    for (int q = 0; q < 2; ++q) {
        const int gn = (tn >> 1) + (wc >> 1) + q * 16 + r15;
        const float bi_ = bWi[gn] + bUi[gn];
        const float bc_ = bWc[gn] + bUc[gn];
        #pragma unroll
        for (int m = 0; m < 8; ++m) {
            const int gm = tm + wr + m * 16 + rg4;
            #pragma unroll
            for (int r = 0; r < 4; ++r) {
                const float zi = acc[m][2 * q][r]     + bi_;
                const float zc = acc[m][2 * q + 1][r] + bc_;
                Cout[(size_t)(gm + r) * D_DIM + gn] = __expf(zi) * fast_tanh(zc);
            }
        }
    }
}

// ---------------- last-timestep o-gate: hbuf[b][e] = sig(Zo)*tanh(c) -------

__global__ __launch_bounds__(256)
void last_gate(const float* __restrict__ x, const float* __restrict__ h,
               const float* __restrict__ Wo, const float* __restrict__ bWo,
               const float* __restrict__ Uo, const float* __restrict__ bUo,
               const float* __restrict__ cfull, float* __restrict__ hbuf) {
    const int o    = blockIdx.x * 4 + (threadIdx.x >> 6);
    const int lane = threadIdx.x & 63;
    const int b = o >> 11, e = o & 2047;
    const float* xr = x  + ((size_t)b * D_DIM + (D_DIM - 1)) * D_DIM;
    const float* hr = h  + ((size_t)b * D_DIM + (D_DIM - 1)) * D_DIM;
    const float* wo = Wo + (size_t)e * D_DIM;
    const float* uo = Uo + (size_t)e * D_DIM;
    float s = 0.0f;
    for (int d = lane; d < D_DIM; d += 64)
        s += xr[d] * wo[d] + hr[d] * uo[d];
    #pragma unroll
    for (int off = 32; off; off >>= 1) s += __shfl_down(s, off);
    if (lane == 0) {
        const float zo  = s + bWo[e] + bUo[e];
        const float sig = 1.0f / (1.0f + __expf(-zo));
        const float cv  = cfull[((size_t)b * D_DIM + (D_DIM - 1)) * D_DIM + e];
        hbuf[o] = sig * fast_tanh(cv);
    }
}

// ---------------- final projection: out[b][p] = hbuf[b] . Wp[p] + bp[p] ----

__global__ __launch_bounds__(256)
void proj(const float* __restrict__ hbuf, const float* __restrict__ Wp,
          const float* __restrict__ bp, float* __restrict__ out) {
    const int o    = blockIdx.x * 4 + (threadIdx.x >> 6);
    const int lane = threadIdx.x & 63;
    const int b = o >> 11, p = o & 2047;
    const float* hv = hbuf + (size_t)b * D_DIM;
    const float* wp = Wp   + (size_t)p * D_DIM;
    float s = 0.0f;
    for (int e = lane; e < D_DIM; e += 64)
        s += hv[e] * wp[e];
    #pragma unroll
    for (int off = 32; off; off >>= 1) s += __shfl_down(s, off);
    if (lane == 0) out[o] = s + bp[p];
}

// ---------------- launch ---------------------------------------------------

extern "C" void kernel_launch(void* const* d_in, const int* in_sizes, int n_in,
                              void* d_out, int out_size, void* d_ws, size_t ws_size,
                              hipStream_t stream) {
    const float* x   = (const float*)d_in[0];
    const float* h   = (const float*)d_in[1];
    const float* Wi  = (const float*)d_in[2];  const float* bWi = (const float*)d_in[3];
    const float* Ui  = (const float*)d_in[4];  const float* bUi = (const float*)d_in[5];
    // Wf/bWf/Uf/bUf (6..9) are dead: f-gate multiplies a zero cell state
    const float* Wc  = (const float*)d_in[10]; const float* bWc = (const float*)d_in[11];
    const float* Uc  = (const float*)d_in[12]; const float* bUc = (const float*)d_in[13];
    const float* Wo  = (const float*)d_in[14]; const float* bWo = (const float*)d_in[15];
    const float* Uo  = (const float*)d_in[16]; const float* bUo = (const float*)d_in[17];
    const float* Wp  = (const float*)d_in[18]; const float* bp  = (const float*)d_in[19];

    float* out = (float*)d_out;               // [0,8192) hidden_state, then c
    char*  ws  = (char*)d_ws;

    __hip_bfloat16* Abf  = (__hip_bfloat16*)ws;                          // 64 MiB
    __hip_bfloat16* Bpk  = (__hip_bfloat16*)(ws + ((size_t)64 << 20));   // 32 MiB
    float*          hbuf = (float*)(ws + ((size_t)96 << 20));            // 32 KiB

    // 1) convert/pack to bf16
    pack2<<<16384, 256, 0, stream>>>(x, h, Abf, M_TOT * KTOT / 8);
    pack_gates<<<8192, 256, 0, stream>>>(Wi, Ui, Wc, Uc, Bpk);

    // 2) fused dual-gate 8-phase GEMM -> c
    gemm8<<<(M_TOT / 256) * (NPACK / 256), 512, 0, stream>>>(
        Abf, Bpk, bWi, bUi, bWc, bUc, out + 8192);

    // 3) last-timestep o-gate (reads c from out), then 4) projection
    last_gate<<<2048, 256, 0, stream>>>(x, h, Wo, bWo, Uo, bUo, out + 8192,
                                        (float*)hbuf);
    proj<<<2048, 256, 0, stream>>>(hbuf, Wp, bp, out);
}